// Round 1
// baseline (287.811 us; speedup 1.0000x reference)
//
#include <hip/hip_runtime.h>
#include <hip/hip_bf16.h>
#include <stdint.h>

#define B_ 8
#define K_ 2048
#define D_ 1024
#define NC 8
#define TC (K_ / NC)   // 256 timesteps per chunk

typedef float v4f __attribute__((ext_vector_type(4)));
typedef short v8s __attribute__((ext_vector_type(8)));

__device__ __forceinline__ unsigned short f2bf(float f) {
    __hip_bfloat16 h = __float2bfloat16(f);
    return *reinterpret_cast<unsigned short*>(&h);
}

__device__ __forceinline__ void async_ld16(const void* g, void* l) {
    __builtin_amdgcn_global_load_lds(
        (__attribute__((address_space(1))) void*)(void*)g,
        (__attribute__((address_space(3))) void*)l,
        16, 0, 0);
}

// ---------------- converter: W (fp32 [K][K]) -> bf16 [K][K] ----------------
__global__ void conv_w(const float* __restrict__ W, unsigned short* __restrict__ Wb) {
    int i = (blockIdx.x * 256 + threadIdx.x) * 4;
    float4 v = *(const float4*)(W + i);
    ushort4 o;
    o.x = f2bf(v.x); o.y = f2bf(v.y); o.z = f2bf(v.z); o.w = f2bf(v.w);
    *(ushort4*)(Wb + i) = o;
}

// ---------- converter+transpose: x fp32 [B][K][D] -> xT bf16 [B][D][K] ----------
__global__ void conv_x_t(const float* __restrict__ x, unsigned short* __restrict__ xT) {
    const int k0 = blockIdx.x * 64, d0 = blockIdx.y * 64, bb = blockIdx.z;
    __shared__ unsigned short tile[64][68];   // pad 68 to break bank alignment
    const int tid = threadIdx.x;
    const int tx = tid & 15, ty = tid >> 4;
    const float* xp = x + (size_t)bb * K_ * D_;
#pragma unroll
    for (int r = 0; r < 4; r++) {
        int row = ty + r * 16;
        float4 v = *(const float4*)(xp + (size_t)(k0 + row) * D_ + d0 + tx * 4);
        tile[row][tx * 4 + 0] = f2bf(v.x);
        tile[row][tx * 4 + 1] = f2bf(v.y);
        tile[row][tx * 4 + 2] = f2bf(v.z);
        tile[row][tx * 4 + 3] = f2bf(v.w);
    }
    __syncthreads();
    unsigned short* op = xT + (size_t)bb * D_ * K_;
#pragma unroll
    for (int r = 0; r < 4; r++) {
        int dcol = ty + r * 16;
        ushort4 u;
        u.x = tile[tx * 4 + 0][dcol];
        u.y = tile[tx * 4 + 1][dcol];
        u.z = tile[tx * 4 + 2][dcol];
        u.w = tile[tx * 4 + 3][dcol];
        *(ushort4*)(op + (size_t)(d0 + dcol) * K_ + k0 + tx * 4) = u;
    }
}

// ---------------- GEMM + bias + sigmoid: lam[b][t][d] ----------------
// A = Wb [t][k] (k contig), B^T = xT[b] [d][k] (k contig). 128x128 tile, BK=32.
__launch_bounds__(256)
__global__ void gemm_sig(const unsigned short* __restrict__ Wb,
                         const unsigned short* __restrict__ xT,
                         const float* __restrict__ bias,
                         float* __restrict__ lam) {
    const int tM = blockIdx.x, tN = blockIdx.y, bb = blockIdx.z;
    __shared__ unsigned short As[128 * 32];
    __shared__ unsigned short Bs[128 * 32];
    const int tid = threadIdx.x;
    const int w = tid >> 6;          // wave 0..3
    const int lane = tid & 63;
    const int wm = w >> 1, wn = w & 1;
    const int quad = lane >> 4;
    const int l16 = lane & 15;

    v4f acc[4][4];
#pragma unroll
    for (int i = 0; i < 4; i++)
#pragma unroll
        for (int j = 0; j < 4; j++) acc[i][j] = (v4f)0.f;

    const unsigned short* Ag = Wb + (size_t)(tM * 128) * K_;
    const unsigned short* Bg = xT + (size_t)bb * D_ * K_ + (size_t)(tN * 128) * K_;

    const int srow = lane >> 2;          // 0..15
    const int schunk = (lane & 3) * 8;   // element offset within 32-wide row

    for (int k0 = 0; k0 < K_; k0 += 32) {
#pragma unroll
        for (int q = 0; q < 2; q++) {
            int rb = (q * 4 + w) * 16;   // 16-row group base
            async_ld16(Ag + (size_t)(rb + srow) * K_ + k0 + schunk, As + rb * 32);
            async_ld16(Bg + (size_t)(rb + srow) * K_ + k0 + schunk, Bs + rb * 32);
        }
        __syncthreads();
        v8s af[4], bfr[4];
#pragma unroll
        for (int i = 0; i < 4; i++)
            af[i] = *(const v8s*)(As + (wm * 64 + i * 16 + l16) * 32 + quad * 8);
#pragma unroll
        for (int j = 0; j < 4; j++)
            bfr[j] = *(const v8s*)(Bs + (wn * 64 + j * 16 + l16) * 32 + quad * 8);
#pragma unroll
        for (int i = 0; i < 4; i++)
#pragma unroll
            for (int j = 0; j < 4; j++)
                acc[i][j] = __builtin_amdgcn_mfma_f32_16x16x32_bf16(af[i], bfr[j], acc[i][j], 0, 0, 0);
        __syncthreads();
    }

    float* out = lam + (size_t)bb * K_ * D_;
#pragma unroll
    for (int i = 0; i < 4; i++) {
        int rowb = tM * 128 + wm * 64 + i * 16 + quad * 4;
#pragma unroll
        for (int r = 0; r < 4; r++) {
            float bt = bias[rowb + r];
#pragma unroll
            for (int j = 0; j < 4; j++) {
                int col = tN * 128 + wn * 64 + j * 16 + l16;
                float v = acc[i][j][r] + bt;
                out[(size_t)(rowb + r) * D_ + col] = 1.f / (1.f + __expf(-v));
            }
        }
    }
}

// -------- scan pass 1: per-(b,chunk,d) affine composition (A,U) --------
__global__ void scan_pass1(const float* __restrict__ lam, const float* __restrict__ x,
                           float* __restrict__ Ac, float* __restrict__ Uc) {
    int id = blockIdx.x * 256 + threadIdx.x;   // B*NC*D = 65536
    int d = id & (D_ - 1);
    int c = (id >> 10) & (NC - 1);
    int bb = id >> 13;
    const float* lp = lam + (size_t)bb * K_ * D_ + (size_t)c * TC * D_ + d;
    const float* xp = x   + (size_t)bb * K_ * D_ + (size_t)c * TC * D_ + d;
    float A = 1.f, U = 0.f;
#pragma unroll 4
    for (int t = 0; t < TC; t++) {
        float l = lp[(size_t)t * D_];
        float xv = xp[(size_t)t * D_];
        A *= l;
        U = l * U + (1.f - l) * xv;
    }
    Ac[id] = A;
    Uc[id] = U;
}

// -------- scan pass 2: chunk-level exclusive prefix (entry state per chunk) --------
__global__ void scan_pass2(const float* __restrict__ Ac, const float* __restrict__ Uc,
                           float* __restrict__ Sin) {
    int id = blockIdx.x * 256 + threadIdx.x;   // B*D = 8192
    int d = id & (D_ - 1);
    int bb = id >> 10;
    float s = 0.f;
#pragma unroll
    for (int c = 0; c < NC; c++) {
        int idx = (bb * NC + c) * D_ + d;
        Sin[idx] = s;
        s = Ac[idx] * s + Uc[idx];
    }
}

// -------- scan pass 3: replay chunk with entry state, overwrite lam (=d_out) in place --------
__global__ void scan_pass3(const float* __restrict__ x, const float* __restrict__ Sin,
                           float* __restrict__ lamout) {
    int id = blockIdx.x * 256 + threadIdx.x;   // 65536
    int d = id & (D_ - 1);
    int c = (id >> 10) & (NC - 1);
    int bb = id >> 13;
    float* lp = lamout + (size_t)bb * K_ * D_ + (size_t)c * TC * D_ + d;
    const float* xp = x + (size_t)bb * K_ * D_ + (size_t)c * TC * D_ + d;
    float s = Sin[id];
#pragma unroll 4
    for (int t = 0; t < TC; t++) {
        float l = lp[(size_t)t * D_];
        float xv = xp[(size_t)t * D_];
        s = l * s + (1.f - l) * xv;
        lp[(size_t)t * D_] = s;   // read-before-write, same thread, same address
    }
}

extern "C" void kernel_launch(void* const* d_in, const int* in_sizes, int n_in,
                              void* d_out, int out_size, void* d_ws, size_t ws_size,
                              hipStream_t stream) {
    const float* x    = (const float*)d_in[0];
    const float* W    = (const float*)d_in[1];
    const float* bias = (const float*)d_in[2];
    float* out = (float*)d_out;
    char* ws = (char*)d_ws;

    unsigned short* xT = (unsigned short*)ws;                       // 32 MiB  [B][D][K] bf16
    unsigned short* Wb = (unsigned short*)(ws + 33554432);          // 8 MiB   [K][K] bf16
    float* Ac  = (float*)(ws + 41943040);                           // 256 KiB
    float* Uc  = (float*)(ws + 41943040 + 262144);                  // 256 KiB
    float* Sin = (float*)(ws + 41943040 + 524288);                  // 256 KiB

    conv_w<<<dim3(K_ * K_ / 4 / 256), 256, 0, stream>>>(W, Wb);
    conv_x_t<<<dim3(K_ / 64, D_ / 64, B_), 256, 0, stream>>>(x, xT);
    // lam goes into d_out; pass3 overwrites it in place with the final scan output
    gemm_sig<<<dim3(K_ / 128, D_ / 128, B_), 256, 0, stream>>>(Wb, xT, bias, out);
    scan_pass1<<<dim3(B_ * NC * D_ / 256), 256, 0, stream>>>(out, x, Ac, Uc);
    scan_pass2<<<dim3(B_ * D_ / 256), 256, 0, stream>>>(Ac, Uc, Sin);
    scan_pass3<<<dim3(B_ * NC * D_ / 256), 256, 0, stream>>>(x, Sin, out);
}

// Round 2
// 281.628 us; speedup vs baseline: 1.0220x; 1.0220x over previous
//
#include <hip/hip_runtime.h>
#include <hip/hip_bf16.h>
#include <stdint.h>

#define B_ 8
#define K_ 2048
#define D_ 1024
#define NC 32
#define TC (K_ / NC)   // 64 timesteps per chunk

typedef float v4f __attribute__((ext_vector_type(4)));
typedef short v8s __attribute__((ext_vector_type(8)));

__device__ __forceinline__ unsigned short f2bf(float f) {
    __hip_bfloat16 h = __float2bfloat16(f);
    return *reinterpret_cast<unsigned short*>(&h);
}

__device__ __forceinline__ void async_ld16(const void* g, void* l) {
    __builtin_amdgcn_global_load_lds(
        (__attribute__((address_space(1))) void*)(void*)g,
        (__attribute__((address_space(3))) void*)l,
        16, 0, 0);
}

// ---------------- converter: W (fp32 [K][K]) -> bf16 [K][K] ----------------
__global__ void conv_w(const float* __restrict__ W, unsigned short* __restrict__ Wb) {
    int i = (blockIdx.x * 256 + threadIdx.x) * 4;
    float4 v = *(const float4*)(W + i);
    ushort4 o;
    o.x = f2bf(v.x); o.y = f2bf(v.y); o.z = f2bf(v.z); o.w = f2bf(v.w);
    *(ushort4*)(Wb + i) = o;
}

// ---------- converter+transpose: x fp32 [B][K][D] -> xT bf16 [B][D][K] ----------
__global__ void conv_x_t(const float* __restrict__ x, unsigned short* __restrict__ xT) {
    const int k0 = blockIdx.x * 64, d0 = blockIdx.y * 64, bb = blockIdx.z;
    __shared__ unsigned short tile[64][68];   // pad 68 to break bank alignment
    const int tid = threadIdx.x;
    const int tx = tid & 15, ty = tid >> 4;
    const float* xp = x + (size_t)bb * K_ * D_;
#pragma unroll
    for (int r = 0; r < 4; r++) {
        int row = ty + r * 16;
        float4 v = *(const float4*)(xp + (size_t)(k0 + row) * D_ + d0 + tx * 4);
        tile[row][tx * 4 + 0] = f2bf(v.x);
        tile[row][tx * 4 + 1] = f2bf(v.y);
        tile[row][tx * 4 + 2] = f2bf(v.z);
        tile[row][tx * 4 + 3] = f2bf(v.w);
    }
    __syncthreads();
    unsigned short* op = xT + (size_t)bb * D_ * K_;
#pragma unroll
    for (int r = 0; r < 4; r++) {
        int dcol = ty + r * 16;
        ushort4 u;
        u.x = tile[tx * 4 + 0][dcol];
        u.y = tile[tx * 4 + 1][dcol];
        u.z = tile[tx * 4 + 2][dcol];
        u.w = tile[tx * 4 + 3][dcol];
        *(ushort4*)(op + (size_t)(d0 + dcol) * K_ + k0 + tx * 4) = u;
    }
}

// ---------------- GEMM + bias + sigmoid: lam[b][t][d] ----------------
// A = Wb [t][k] (k contig), B^T = xT[b] [d][k] (k contig). 128x128 tile, BK=32.
// LDS layout XOR-swizzled: (row r, k-chunk c) stored at slot s = c ^ ((r>>1)&3)
// -> every 8-lane phase of a ds_read_b128 hits all 8 bank groups (conflict-free).
__launch_bounds__(256)
__global__ void gemm_sig(const unsigned short* __restrict__ Wb,
                         const unsigned short* __restrict__ xT,
                         const float* __restrict__ bias,
                         float* __restrict__ lam) {
    const int tM = blockIdx.x, tN = blockIdx.y, bb = blockIdx.z;
    __shared__ unsigned short As[128 * 32];
    __shared__ unsigned short Bs[128 * 32];
    const int tid = threadIdx.x;
    const int w = tid >> 6;          // wave 0..3
    const int lane = tid & 63;
    const int wm = w >> 1, wn = w & 1;
    const int quad = lane >> 4;
    const int l16 = lane & 15;

    v4f acc[4][4];
#pragma unroll
    for (int i = 0; i < 4; i++)
#pragma unroll
        for (int j = 0; j < 4; j++) acc[i][j] = (v4f)0.f;

    const unsigned short* Ag = Wb + (size_t)(tM * 128) * K_;
    const unsigned short* Bg = xT + (size_t)bb * D_ * K_ + (size_t)(tN * 128) * K_;

    const int srow = lane >> 2;                                    // 0..15
    const int schunk = (((lane & 3) ^ ((lane >> 3) & 3)) * 8);     // swizzled k-chunk source
    const int sw8 = (quad ^ ((l16 >> 1) & 3)) * 8;                 // swizzled read slot

    for (int k0 = 0; k0 < K_; k0 += 32) {
#pragma unroll
        for (int q = 0; q < 2; q++) {
            int rb = (q * 4 + w) * 16;   // 16-row group base
            async_ld16(Ag + (size_t)(rb + srow) * K_ + k0 + schunk, As + rb * 32);
            async_ld16(Bg + (size_t)(rb + srow) * K_ + k0 + schunk, Bs + rb * 32);
        }
        __syncthreads();
        v8s af[4], bfr[4];
#pragma unroll
        for (int i = 0; i < 4; i++)
            af[i] = *(const v8s*)(As + (wm * 64 + i * 16 + l16) * 32 + sw8);
#pragma unroll
        for (int j = 0; j < 4; j++)
            bfr[j] = *(const v8s*)(Bs + (wn * 64 + j * 16 + l16) * 32 + sw8);
#pragma unroll
        for (int i = 0; i < 4; i++)
#pragma unroll
            for (int j = 0; j < 4; j++)
                acc[i][j] = __builtin_amdgcn_mfma_f32_16x16x32_bf16(af[i], bfr[j], acc[i][j], 0, 0, 0);
        __syncthreads();
    }

    float* out = lam + (size_t)bb * K_ * D_;
#pragma unroll
    for (int i = 0; i < 4; i++) {
        int rowb = tM * 128 + wm * 64 + i * 16 + quad * 4;
#pragma unroll
        for (int r = 0; r < 4; r++) {
            float bt = bias[rowb + r];
#pragma unroll
            for (int j = 0; j < 4; j++) {
                int col = tN * 128 + wn * 64 + j * 16 + l16;
                float v = acc[i][j][r] + bt;
                out[(size_t)(rowb + r) * D_ + col] = 1.f / (1.f + __expf(-v));
            }
        }
    }
}

// -------- scan pass 1: per-(b,chunk,d) affine composition (A,U) --------
__global__ void scan_pass1(const float* __restrict__ lam, const float* __restrict__ x,
                           float* __restrict__ Ac, float* __restrict__ Uc) {
    int id = blockIdx.x * 256 + threadIdx.x;   // B*NC*D = 262144
    int d = id & (D_ - 1);
    int c = (id >> 10) & (NC - 1);
    int bb = id >> 15;
    const float* lp = lam + (size_t)bb * K_ * D_ + (size_t)c * TC * D_ + d;
    const float* xp = x   + (size_t)bb * K_ * D_ + (size_t)c * TC * D_ + d;
    float A = 1.f, U = 0.f;
#pragma unroll 8
    for (int t = 0; t < TC; t++) {
        float l = lp[(size_t)t * D_];
        float xv = xp[(size_t)t * D_];
        A *= l;
        U = l * U + (1.f - l) * xv;
    }
    Ac[id] = A;
    Uc[id] = U;
}

// -------- scan pass 2: chunk-level exclusive prefix (entry state per chunk) --------
__global__ void scan_pass2(const float* __restrict__ Ac, const float* __restrict__ Uc,
                           float* __restrict__ Sin) {
    int id = blockIdx.x * 256 + threadIdx.x;   // B*D = 8192
    int d = id & (D_ - 1);
    int bb = id >> 10;
    float s = 0.f;
#pragma unroll
    for (int c = 0; c < NC; c++) {
        int idx = (bb * NC + c) * D_ + d;
        Sin[idx] = s;
        s = Ac[idx] * s + Uc[idx];
    }
}

// -------- scan pass 3: replay chunk with entry state, overwrite lam (=d_out) in place --------
__global__ void scan_pass3(const float* __restrict__ x, const float* __restrict__ Sin,
                           float* __restrict__ lamout) {
    int id = blockIdx.x * 256 + threadIdx.x;   // 262144
    int d = id & (D_ - 1);
    int c = (id >> 10) & (NC - 1);
    int bb = id >> 15;
    float* lp = lamout + (size_t)bb * K_ * D_ + (size_t)c * TC * D_ + d;
    const float* xp = x + (size_t)bb * K_ * D_ + (size_t)c * TC * D_ + d;
    float s = Sin[id];
#pragma unroll 8
    for (int t = 0; t < TC; t++) {
        float l = lp[(size_t)t * D_];
        float xv = xp[(size_t)t * D_];
        s = l * s + (1.f - l) * xv;
        lp[(size_t)t * D_] = s;   // read-before-write, same thread, same address
    }
}

extern "C" void kernel_launch(void* const* d_in, const int* in_sizes, int n_in,
                              void* d_out, int out_size, void* d_ws, size_t ws_size,
                              hipStream_t stream) {
    const float* x    = (const float*)d_in[0];
    const float* W    = (const float*)d_in[1];
    const float* bias = (const float*)d_in[2];
    float* out = (float*)d_out;
    char* ws = (char*)d_ws;

    unsigned short* xT = (unsigned short*)ws;                       // 32 MiB  [B][D][K] bf16
    unsigned short* Wb = (unsigned short*)(ws + 33554432);          // 8 MiB   [K][K] bf16
    // Ac/Uc/Sin (1 MiB each) overlay Wb's region — Wb is dead once gemm_sig completes,
    // and stream ordering guarantees gemm_sig finishes before scan_pass1 starts.
    float* Ac  = (float*)(ws + 33554432);
    float* Uc  = (float*)(ws + 33554432 + 1048576);
    float* Sin = (float*)(ws + 33554432 + 2097152);

    conv_w<<<dim3(K_ * K_ / 4 / 256), 256, 0, stream>>>(W, Wb);
    conv_x_t<<<dim3(K_ / 64, D_ / 64, B_), 256, 0, stream>>>(x, xT);
    // lam goes into d_out; pass3 overwrites it in place with the final scan output
    gemm_sig<<<dim3(K_ / 128, D_ / 128, B_), 256, 0, stream>>>(Wb, xT, bias, out);
    scan_pass1<<<dim3(B_ * NC * D_ / 256), 256, 0, stream>>>(out, x, Ac, Uc);
    scan_pass2<<<dim3(B_ * D_ / 256), 256, 0, stream>>>(Ac, Uc, Sin);
    scan_pass3<<<dim3(B_ * NC * D_ / 256), 256, 0, stream>>>(x, Sin, out);
}

// Round 3
// 277.347 us; speedup vs baseline: 1.0377x; 1.0154x over previous
//
#include <hip/hip_runtime.h>
#include <hip/hip_bf16.h>
#include <stdint.h>

#define B_ 8
#define K_ 2048
#define D_ 1024
#define NC 32
#define TC (K_ / NC)   // 64 timesteps per chunk

typedef float v4f __attribute__((ext_vector_type(4)));
typedef short v8s __attribute__((ext_vector_type(8)));

__device__ __forceinline__ unsigned short f2bf(float f) {
    __hip_bfloat16 h = __float2bfloat16(f);
    return *reinterpret_cast<unsigned short*>(&h);
}

__device__ __forceinline__ void async_ld16(const void* g, void* l) {
    __builtin_amdgcn_global_load_lds(
        (__attribute__((address_space(1))) void*)(void*)g,
        (__attribute__((address_space(3))) void*)l,
        16, 0, 0);
}

// ---------------- converter: W (fp32 [K][K]) -> bf16 [K][K] ----------------
__global__ void conv_w(const float* __restrict__ W, unsigned short* __restrict__ Wb) {
    int i = (blockIdx.x * 256 + threadIdx.x) * 4;
    float4 v = *(const float4*)(W + i);
    ushort4 o;
    o.x = f2bf(v.x); o.y = f2bf(v.y); o.z = f2bf(v.z); o.w = f2bf(v.w);
    *(ushort4*)(Wb + i) = o;
}

// ---------- converter+transpose: x fp32 [B][K][D] -> xT bf16 [B][D][K] ----------
__global__ void conv_x_t(const float* __restrict__ x, unsigned short* __restrict__ xT) {
    const int k0 = blockIdx.x * 64, d0 = blockIdx.y * 64, bb = blockIdx.z;
    __shared__ unsigned short tile[64][68];   // pad 68 to break bank alignment
    const int tid = threadIdx.x;
    const int tx = tid & 15, ty = tid >> 4;
    const float* xp = x + (size_t)bb * K_ * D_;
#pragma unroll
    for (int r = 0; r < 4; r++) {
        int row = ty + r * 16;
        float4 v = *(const float4*)(xp + (size_t)(k0 + row) * D_ + d0 + tx * 4);
        tile[row][tx * 4 + 0] = f2bf(v.x);
        tile[row][tx * 4 + 1] = f2bf(v.y);
        tile[row][tx * 4 + 2] = f2bf(v.z);
        tile[row][tx * 4 + 3] = f2bf(v.w);
    }
    __syncthreads();
    unsigned short* op = xT + (size_t)bb * D_ * K_;
#pragma unroll
    for (int r = 0; r < 4; r++) {
        int dcol = ty + r * 16;
        ushort4 u;
        u.x = tile[tx * 4 + 0][dcol];
        u.y = tile[tx * 4 + 1][dcol];
        u.z = tile[tx * 4 + 2][dcol];
        u.w = tile[tx * 4 + 3][dcol];
        *(ushort4*)(op + (size_t)(d0 + dcol) * K_ + k0 + tx * 4) = u;
    }
}

// ---------------- GEMM + bias + sigmoid: lam[b][t][d] ----------------
// A = Wb [t][k] (k contig), B^T = xT[b] [d][k] (k contig). 128x128 tile.
// BK=64 staged as TWO back-to-back BK=32 sub-buffers (row stride stays 64 B;
// lane-linear global_load_lds source order — R2 showed XOR-permuting the
// source lanes costs ~13%, worse than the bank conflicts it removes).
// Halves the barrier count vs BK=32: 32 iterations instead of 64.
__launch_bounds__(256)
__global__ void gemm_sig(const unsigned short* __restrict__ Wb,
                         const unsigned short* __restrict__ xT,
                         const float* __restrict__ bias,
                         float* __restrict__ lam) {
    const int tM = blockIdx.x, tN = blockIdx.y, bb = blockIdx.z;
    __shared__ unsigned short As[2][128 * 32];
    __shared__ unsigned short Bs[2][128 * 32];
    const int tid = threadIdx.x;
    const int w = tid >> 6;          // wave 0..3
    const int lane = tid & 63;
    const int wm = w >> 1, wn = w & 1;
    const int quad = lane >> 4;
    const int l16 = lane & 15;

    v4f acc[4][4];
#pragma unroll
    for (int i = 0; i < 4; i++)
#pragma unroll
        for (int j = 0; j < 4; j++) acc[i][j] = (v4f)0.f;

    const unsigned short* Ag = Wb + (size_t)(tM * 128) * K_;
    const unsigned short* Bg = xT + (size_t)bb * D_ * K_ + (size_t)(tN * 128) * K_;

    const int srow = lane >> 2;          // 0..15
    const int schunk = (lane & 3) * 8;   // lane-linear source (coalescing-friendly)

    for (int k0 = 0; k0 < K_; k0 += 64) {
#pragma unroll
        for (int h = 0; h < 2; h++) {
#pragma unroll
            for (int q = 0; q < 2; q++) {
                int rb = (q * 4 + w) * 16;   // 16-row group base
                async_ld16(Ag + (size_t)(rb + srow) * K_ + k0 + h * 32 + schunk, &As[h][rb * 32]);
                async_ld16(Bg + (size_t)(rb + srow) * K_ + k0 + h * 32 + schunk, &Bs[h][rb * 32]);
            }
        }
        __syncthreads();
#pragma unroll
        for (int h = 0; h < 2; h++) {
            v8s af[4], bfr[4];
#pragma unroll
            for (int i = 0; i < 4; i++)
                af[i] = *(const v8s*)(&As[h][(wm * 64 + i * 16 + l16) * 32 + quad * 8]);
#pragma unroll
            for (int j = 0; j < 4; j++)
                bfr[j] = *(const v8s*)(&Bs[h][(wn * 64 + j * 16 + l16) * 32 + quad * 8]);
#pragma unroll
            for (int i = 0; i < 4; i++)
#pragma unroll
                for (int j = 0; j < 4; j++)
                    acc[i][j] = __builtin_amdgcn_mfma_f32_16x16x32_bf16(af[i], bfr[j], acc[i][j], 0, 0, 0);
        }
        __syncthreads();
    }

    float* out = lam + (size_t)bb * K_ * D_;
#pragma unroll
    for (int i = 0; i < 4; i++) {
        int rowb = tM * 128 + wm * 64 + i * 16 + quad * 4;
#pragma unroll
        for (int r = 0; r < 4; r++) {
            float bt = bias[rowb + r];
#pragma unroll
            for (int j = 0; j < 4; j++) {
                int col = tN * 128 + wn * 64 + j * 16 + l16;
                float v = acc[i][j][r] + bt;
                out[(size_t)(rowb + r) * D_ + col] = 1.f / (1.f + __expf(-v));
            }
        }
    }
}

// -------- scan pass 1: per-(b,chunk,d2) affine composition (A,U), float2/lane --------
__global__ void scan_pass1(const float* __restrict__ lam, const float* __restrict__ x,
                           float* __restrict__ Ac, float* __restrict__ Uc) {
    int id = blockIdx.x * 256 + threadIdx.x;   // B*NC*D/2 = 131072
    int d2 = (id & 511) * 2;
    int c = (id >> 9) & (NC - 1);
    int bb = id >> 14;
    const float* lp = lam + ((size_t)bb * K_ + (size_t)c * TC) * D_ + d2;
    const float* xp = x   + ((size_t)bb * K_ + (size_t)c * TC) * D_ + d2;
    float2 A = make_float2(1.f, 1.f), U = make_float2(0.f, 0.f);
#pragma unroll 8
    for (int t = 0; t < TC; t++) {
        float2 l  = *(const float2*)(lp + (size_t)t * D_);
        float2 xv = *(const float2*)(xp + (size_t)t * D_);
        A.x *= l.x; A.y *= l.y;
        U.x = l.x * U.x + (1.f - l.x) * xv.x;
        U.y = l.y * U.y + (1.f - l.y) * xv.y;
    }
    size_t oi = ((size_t)bb * NC + c) * D_ + d2;
    *(float2*)(Ac + oi) = A;
    *(float2*)(Uc + oi) = U;
}

// -------- scan pass 2: chunk-level exclusive prefix (entry state per chunk) --------
__global__ void scan_pass2(const float* __restrict__ Ac, const float* __restrict__ Uc,
                           float* __restrict__ Sin) {
    int id = blockIdx.x * 256 + threadIdx.x;   // B*D = 8192
    int d = id & (D_ - 1);
    int bb = id >> 10;
    float s = 0.f;
#pragma unroll
    for (int c = 0; c < NC; c++) {
        int idx = (bb * NC + c) * D_ + d;
        Sin[idx] = s;
        s = Ac[idx] * s + Uc[idx];
    }
}

// -------- scan pass 3: replay chunk with entry state, float2/lane, in-place over lam --------
__global__ void scan_pass3(const float* __restrict__ x, const float* __restrict__ Sin,
                           float* __restrict__ lamout) {
    int id = blockIdx.x * 256 + threadIdx.x;   // 131072
    int d2 = (id & 511) * 2;
    int c = (id >> 9) & (NC - 1);
    int bb = id >> 14;
    float* lp = lamout + ((size_t)bb * K_ + (size_t)c * TC) * D_ + d2;
    const float* xp = x + ((size_t)bb * K_ + (size_t)c * TC) * D_ + d2;
    size_t si = ((size_t)bb * NC + c) * D_ + d2;
    float2 s = *(const float2*)(Sin + si);
#pragma unroll 8
    for (int t = 0; t < TC; t++) {
        float2 l  = *(const float2*)(lp + (size_t)t * D_);
        float2 xv = *(const float2*)(xp + (size_t)t * D_);
        s.x = l.x * s.x + (1.f - l.x) * xv.x;
        s.y = l.y * s.y + (1.f - l.y) * xv.y;
        *(float2*)(lp + (size_t)t * D_) = s;   // read-before-write, same thread
    }
}

extern "C" void kernel_launch(void* const* d_in, const int* in_sizes, int n_in,
                              void* d_out, int out_size, void* d_ws, size_t ws_size,
                              hipStream_t stream) {
    const float* x    = (const float*)d_in[0];
    const float* W    = (const float*)d_in[1];
    const float* bias = (const float*)d_in[2];
    float* out = (float*)d_out;
    char* ws = (char*)d_ws;

    unsigned short* xT = (unsigned short*)ws;                       // 32 MiB  [B][D][K] bf16
    unsigned short* Wb = (unsigned short*)(ws + 33554432);          // 8 MiB   [K][K] bf16
    // Ac/Uc/Sin (1 MiB each) overlay Wb's region — Wb is dead once gemm_sig completes.
    float* Ac  = (float*)(ws + 33554432);
    float* Uc  = (float*)(ws + 33554432 + 1048576);
    float* Sin = (float*)(ws + 33554432 + 2097152);

    conv_w<<<dim3(K_ * K_ / 4 / 256), 256, 0, stream>>>(W, Wb);
    conv_x_t<<<dim3(K_ / 64, D_ / 64, B_), 256, 0, stream>>>(x, xT);
    // lam goes into d_out; pass3 overwrites it in place with the final scan output
    gemm_sig<<<dim3(K_ / 128, D_ / 128, B_), 256, 0, stream>>>(Wb, xT, bias, out);
    scan_pass1<<<dim3(B_ * NC * D_ / 2 / 256), 256, 0, stream>>>(out, x, Ac, Uc);
    scan_pass2<<<dim3(B_ * D_ / 256), 256, 0, stream>>>(Ac, Uc, Sin);
    scan_pass3<<<dim3(B_ * NC * D_ / 2 / 256), 256, 0, stream>>>(x, Sin, out);
}